// Round 7
// baseline (197.257 us; speedup 1.0000x reference)
//
#include <hip/hip_runtime.h>

static constexpr int N = 4096;
static constexpr int D = 8192;
static constexpr int BLOCK = 256;
static constexpr int CHUNK = 4096;   // floats per chunk (16 KB)

// async global->LDS, 16B per lane (m97-validated path, zero VGPR writeback)
__device__ __forceinline__ void stage16(const float* g, float* l) {
    __builtin_amdgcn_global_load_lds(
        (const __attribute__((address_space(1))) void*)g,
        (__attribute__((address_space(3))) void*)l, 16, 0, 0);
}

// Block handles 2 rows (2048 blocks). Each row = 2 chunks of 4096 floats.
// Chunks streamed via global_load_lds double-buffer: issue stage(c+1),
// barrier (drains c, overlaps c+1 with compute c), compute c from LDS.
// chunk index c: row = c>>1, half = c&1. half==0 -> masked phase (cols 0..4096,
// labels needed, diag lives here); half==1 -> denom-only.
// Self-pair kept in ssum/fcnt/diag; combine fixes analytically.
__global__ __launch_bounds__(BLOCK) void supcon_partial(
    const float* __restrict__ emb,
    const int* __restrict__ labels,
    float4* __restrict__ wsA)          // [N] {denom, ssum, fcnt, diag}
{
    __shared__ float buf[2][CHUNK];    // 32 KB double buffer
    __shared__ float4 sred[2][4];

    const int tid = threadIdx.x;
    const int r0 = blockIdx.x * 2;     // rows r0, r0+1
    const float* base = emb + (size_t)r0 * D;

    // labels: same columns [0,4096) for both rows' masked chunks; prefetch once
    const int4* labp = reinterpret_cast<const int4*>(labels);
    int4 lab4[4];
    #pragma unroll
    for (int i = 0; i < 4; ++i)
        lab4[i] = labp[i * BLOCK + tid];
    const int labA = labels[r0];
    const int labB = labels[r0 + 1];

    // stage chunk 0
    #pragma unroll
    for (int i = 0; i < 4; ++i)
        stage16(base + (i * BLOCK + tid) * 4, &buf[0][(i * BLOCK + tid) * 4]);

    float denom[2] = {0.f, 0.f}, ssum[2] = {0.f, 0.f};
    float fcnt[2] = {0.f, 0.f}, diag[2] = {0.f, 0.f};

    #pragma unroll
    for (int c = 0; c < 4; ++c) {
        if (c < 3) {                   // issue next chunk's stage (fire-and-forget)
            const float* src = base + (size_t)(c + 1) * CHUNK;
            float* dst = buf[(c + 1) & 1];
            #pragma unroll
            for (int i = 0; i < 4; ++i)
                stage16(src + (i * BLOCK + tid) * 4, &dst[(i * BLOCK + tid) * 4]);
        }
        __syncthreads();               // drains vmcnt: chunk c ready; c+1 overlaps compute
        const int r = c >> 1;          // 0 or 1 (row index within block)
        const float* cb = buf[c & 1];
        const int lab_i = r ? labB : labA;
        const int row = r0 + r;
        if ((c & 1) == 0) {            // masked half: cols [0, 4096)
            #pragma unroll
            for (int i = 0; i < 4; ++i) {
                const int p = i * BLOCK + tid;               // float4 position
                const float4 v = reinterpret_cast<const float4*>(cb)[p];
                const int4 lj = lab4[i];
                const int j0 = p * 4;                        // global column
                const float xs[4] = {v.x, v.y, v.z, v.w};
                const int   ls[4] = {lj.x, lj.y, lj.z, lj.w};
                #pragma unroll
                for (int k = 0; k < 4; ++k) {
                    float a = __expf(xs[k] * xs[k] * 0.1f);
                    denom[r] += a;
                    float b = __expf(a * 0.1f);
                    bool m = (ls[k] == lab_i);
                    ssum[r] += m ? b : 0.f;
                    fcnt[r] += m ? 1.f : 0.f;
                    diag[r] += (j0 + k == row) ? a : 0.f;
                }
            }
        } else {                       // denom-only half: cols [4096, 8192)
            #pragma unroll
            for (int i = 0; i < 4; ++i) {
                const int p = i * BLOCK + tid;
                const float4 v = reinterpret_cast<const float4*>(cb)[p];
                denom[r] += __expf(v.x * v.x * 0.1f);
                denom[r] += __expf(v.y * v.y * 0.1f);
                denom[r] += __expf(v.z * v.z * 0.1f);
                denom[r] += __expf(v.w * v.w * 0.1f);
            }
        }
        __syncthreads();               // buffer reuse safety
    }

    // reduce both rows: wave shuffle then cross-wave LDS
    #pragma unroll
    for (int r = 0; r < 2; ++r) {
        float dn = denom[r], sv = ssum[r], fc = fcnt[r], dg = diag[r];
        #pragma unroll
        for (int off = 32; off > 0; off >>= 1) {
            dn += __shfl_down(dn, off);
            sv += __shfl_down(sv, off);
            fc += __shfl_down(fc, off);
            dg += __shfl_down(dg, off);
        }
        if ((tid & 63) == 0)
            sred[r][tid >> 6] = make_float4(dn, sv, fc, dg);
    }
    __syncthreads();
    if (tid < 2) {
        float4 t = sred[tid][0];
        #pragma unroll
        for (int w = 1; w < 4; ++w) {
            const float4 s = sred[tid][w];
            t.x += s.x; t.y += s.y; t.z += s.z; t.w += s.w;
        }
        wsA[r0 + tid] = t;
    }
}

// 16 blocks x 256: per-row log expr -> block reduce -> atomic
__global__ __launch_bounds__(256) void supcon_combine(
    const float4* __restrict__ wsA,
    float* __restrict__ out)
{
    const int row = blockIdx.x * 256 + threadIdx.x;
    const float4 p = wsA[row];
    const float denom = p.x - p.w;                     // subtract A[i,i]
    const float ssum  = p.y - __expf(p.w * 0.1f);      // remove self term
    const float fcnt  = p.z - 1.f;                     // remove self match
    float val = __logf(ssum) - __logf(denom) - __logf(fcnt);

    #pragma unroll
    for (int off = 32; off > 0; off >>= 1)
        val += __shfl_down(val, off);
    __shared__ float sb[4];
    if ((threadIdx.x & 63) == 0) sb[threadIdx.x >> 6] = val;
    __syncthreads();
    if (threadIdx.x == 0)
        atomicAdd(out, sb[0] + sb[1] + sb[2] + sb[3]);
}

extern "C" void kernel_launch(void* const* d_in, const int* in_sizes, int n_in,
                              void* d_out, int out_size, void* d_ws, size_t ws_size,
                              hipStream_t stream) {
    const float* emb  = (const float*)d_in[0];
    const int* labels = (const int*)d_in[1];
    float* out        = (float*)d_out;
    float4* wsA       = (float4*)d_ws;                 // 64 KB

    hipMemsetAsync(out, 0, sizeof(float), stream);     // d_out poisoned pre-launch
    supcon_partial<<<dim3(N / 2), dim3(BLOCK), 0, stream>>>(emb, labels, wsA);
    supcon_combine<<<dim3(N / 256), dim3(256), 0, stream>>>(wsA, out);
}